// Round 1
// baseline (357.027 us; speedup 1.0000x reference)
//
#include <hip/hip_runtime.h>
#include <math.h>

#define NB 8
#define N_SRC 2048
#define N_DST 8192
#define C_SRC 128
#define C_SKIP 64
#define C_IN 192
#define C_H 128
#define N_ROWS (NB * N_DST)   /* 65536 */
#define BN_EPS 1e-5f
#define SLOPE 0.01f
#define GEMM_BLOCKS (N_ROWS / 64)   /* 1024 */

// ---------------------------------------------------------------------------
// KNN: per dst point, 3 nearest src points in its cloud -> idx + normalized w
// ---------------------------------------------------------------------------
__global__ __launch_bounds__(256) void k_knn(const float* __restrict__ pos,
                                             const float* __restrict__ pos_skip,
                                             int* __restrict__ knn_idx,
                                             float* __restrict__ knn_w) {
    __shared__ float sx[N_SRC], sy[N_SRC], sz[N_SRC];
    int cloud = blockIdx.x >> 5;   // 32 blocks of 256 dst points per cloud
    int tile  = blockIdx.x & 31;
    const float* pb = pos + (size_t)cloud * N_SRC * 3;
    for (int i = threadIdx.x; i < N_SRC * 3; i += 256) {
        float v = pb[i];
        int p = i / 3, c = i - p * 3;
        if (c == 0) sx[p] = v; else if (c == 1) sy[p] = v; else sz[p] = v;
    }
    __syncthreads();

    int row = cloud * N_DST + tile * 256 + threadIdx.x;
    float px = pos_skip[row * 3 + 0];
    float py = pos_skip[row * 3 + 1];
    float pz = pos_skip[row * 3 + 2];

    float d0 = 3.4e38f, d1 = 3.4e38f, d2 = 3.4e38f;
    int   i0 = 0, i1 = 0, i2 = 0;
#pragma unroll 4
    for (int j = 0; j < N_SRC; ++j) {
        float dx = px - sx[j], dy = py - sy[j], dz = pz - sz[j];
        float d = dx * dx + dy * dy + dz * dz;
        if (d < d2) {
            if (d < d1) {
                d2 = d1; i2 = i1;
                if (d < d0) { d1 = d0; i1 = i0; d0 = d; i0 = j; }
                else        { d1 = d;  i1 = j; }
            } else { d2 = d; i2 = j; }
        }
    }
    float w0 = 1.f / fmaxf(d0, 1e-16f);
    float w1 = 1.f / fmaxf(d1, 1e-16f);
    float w2 = 1.f / fmaxf(d2, 1e-16f);
    float inv = 1.f / (w0 + w1 + w2);
    knn_idx[row * 3 + 0] = i0;
    knn_idx[row * 3 + 1] = i1;
    knn_idx[row * 3 + 2] = i2;
    knn_w[row * 3 + 0] = w0 * inv;
    knn_w[row * 3 + 1] = w1 * inv;
    knn_w[row * 3 + 2] = w2 * inv;
}

// ---------------------------------------------------------------------------
// Transpose W1 [128][192] -> Wt1 [192][128]
// ---------------------------------------------------------------------------
__global__ void k_prep(const float* __restrict__ W1, float* __restrict__ Wt1) {
    for (int idx = blockIdx.x * 256 + threadIdx.x; idx < C_IN * C_H;
         idx += gridDim.x * 256) {
        int c = idx >> 7, o = idx & 127;
        Wt1[idx] = W1[o * C_IN + c];
    }
}

// ---------------------------------------------------------------------------
// GEMM1: A-tile built in LDS from knn gather + x_skip; z = A @ Wt1 + b1;
// lrelu; write h1 -> out (d_out h region); per-block BN partials.
// ---------------------------------------------------------------------------
__global__ __launch_bounds__(256) void k_gemm1(const float* __restrict__ x,
                                               const float* __restrict__ x_skip,
                                               const int* __restrict__ knn_idx,
                                               const float* __restrict__ knn_w,
                                               const float* __restrict__ Wt,
                                               const float* __restrict__ bias,
                                               float* __restrict__ out,
                                               float* __restrict__ ps,
                                               float* __restrict__ pq) {
    const int LDA = 196;
    __shared__ float A[64 * 196];
    int r0 = blockIdx.x * 64;
    int cloud = r0 / N_DST;
    int tid = threadIdx.x;
    int lane = tid & 63, wid = tid >> 6;
    const float* xb = x + (size_t)cloud * N_SRC * C_SRC;

    for (int rr = wid * 16; rr < wid * 16 + 16; ++rr) {
        int row = r0 + rr;
        int j0 = knn_idx[row * 3 + 0];
        int j1 = knn_idx[row * 3 + 1];
        int j2 = knn_idx[row * 3 + 2];
        float w0 = knn_w[row * 3 + 0];
        float w1 = knn_w[row * 3 + 1];
        float w2 = knn_w[row * 3 + 2];
        const float* x0 = xb + (size_t)j0 * C_SRC;
        const float* x1 = xb + (size_t)j1 * C_SRC;
        const float* x2 = xb + (size_t)j2 * C_SRC;
        A[rr * LDA + lane]       = w0 * x0[lane]      + w1 * x1[lane]      + w2 * x2[lane];
        A[rr * LDA + 64 + lane]  = w0 * x0[64 + lane] + w1 * x1[64 + lane] + w2 * x2[64 + lane];
        A[rr * LDA + 128 + lane] = x_skip[(size_t)row * C_SKIP + lane];
    }
    __syncthreads();

    int tx = tid & 31, ty = tid >> 5;
    float acc[8][4];
    float4 bv = *(const float4*)&bias[tx * 4];
#pragma unroll
    for (int i = 0; i < 8; ++i) {
        acc[i][0] = bv.x; acc[i][1] = bv.y; acc[i][2] = bv.z; acc[i][3] = bv.w;
    }

    for (int c = 0; c < C_IN; c += 4) {
        float4 w0v = *(const float4*)&Wt[(c + 0) * C_H + tx * 4];
        float4 w1v = *(const float4*)&Wt[(c + 1) * C_H + tx * 4];
        float4 w2v = *(const float4*)&Wt[(c + 2) * C_H + tx * 4];
        float4 w3v = *(const float4*)&Wt[(c + 3) * C_H + tx * 4];
#pragma unroll
        for (int i = 0; i < 8; ++i) {
            float4 av = *(const float4*)&A[(ty * 8 + i) * LDA + c];
            acc[i][0] += av.x * w0v.x + av.y * w1v.x + av.z * w2v.x + av.w * w3v.x;
            acc[i][1] += av.x * w0v.y + av.y * w1v.y + av.z * w2v.y + av.w * w3v.y;
            acc[i][2] += av.x * w0v.z + av.y * w1v.z + av.z * w2v.z + av.w * w3v.z;
            acc[i][3] += av.x * w0v.w + av.y * w1v.w + av.z * w2v.w + av.w * w3v.w;
        }
    }

    float pss[4] = {0.f, 0.f, 0.f, 0.f};
    float pqs[4] = {0.f, 0.f, 0.f, 0.f};
#pragma unroll
    for (int i = 0; i < 8; ++i) {
        int row = r0 + ty * 8 + i;
        float4 o;
        float z;
        z = acc[i][0]; z = z > 0.f ? z : SLOPE * z; o.x = z; pss[0] += z; pqs[0] += z * z;
        z = acc[i][1]; z = z > 0.f ? z : SLOPE * z; o.y = z; pss[1] += z; pqs[1] += z * z;
        z = acc[i][2]; z = z > 0.f ? z : SLOPE * z; o.z = z; pss[2] += z; pqs[2] += z * z;
        z = acc[i][3]; z = z > 0.f ? z : SLOPE * z; o.w = z; pss[3] += z; pqs[3] += z * z;
        *(float4*)&out[(size_t)row * C_H + tx * 4] = o;
    }

    __syncthreads();   // done with A as GEMM tile
    float* sS = A;
    float* sQ = A + 1024;
#pragma unroll
    for (int j = 0; j < 4; ++j) {
        sS[ty * 128 + tx * 4 + j] = pss[j];
        sQ[ty * 128 + tx * 4 + j] = pqs[j];
    }
    __syncthreads();
    if (tid < 128) {
        float s = 0.f, q = 0.f;
#pragma unroll
        for (int t = 0; t < 8; ++t) { s += sS[t * 128 + tid]; q += sQ[t * 128 + tid]; }
        ps[blockIdx.x * C_H + tid] = s;
        pq[blockIdx.x * C_H + tid] = q;
    }
}

// ---------------------------------------------------------------------------
// Per-channel reduce of block partials -> BN affine (a = g*rsqrt, c = be-mean*a)
// ---------------------------------------------------------------------------
__global__ __launch_bounds__(256) void k_reduce(const float* __restrict__ ps,
                                                const float* __restrict__ pq,
                                                const float* __restrict__ g,
                                                const float* __restrict__ be,
                                                float* __restrict__ a_out,
                                                float* __restrict__ c_out) {
    int col = blockIdx.x;
    float s = 0.f, q = 0.f;
    for (int b = threadIdx.x; b < GEMM_BLOCKS; b += 256) {
        s += ps[b * C_H + col];
        q += pq[b * C_H + col];
    }
    for (int off = 32; off; off >>= 1) {
        s += __shfl_down(s, off);
        q += __shfl_down(q, off);
    }
    __shared__ float rs[4], rq[4];
    if ((threadIdx.x & 63) == 0) { rs[threadIdx.x >> 6] = s; rq[threadIdx.x >> 6] = q; }
    __syncthreads();
    if (threadIdx.x == 0) {
        s = rs[0] + rs[1] + rs[2] + rs[3];
        q = rq[0] + rq[1] + rq[2] + rq[3];
        float mean = s / (float)N_ROWS;
        float var  = q / (float)N_ROWS - mean * mean;
        float a = g[col] * rsqrtf(var + BN_EPS);
        a_out[col] = a;
        c_out[col] = be[col] - mean * a;
    }
}

// ---------------------------------------------------------------------------
// Fold BN1 affine into W2/b2:  Wt2f[c][o] = W2[o][c]*a1[c];  b2f = b2 + W2@c1
// ---------------------------------------------------------------------------
__global__ __launch_bounds__(256) void k_fold(const float* __restrict__ W2,
                                              const float* __restrict__ b2,
                                              const float* __restrict__ a1,
                                              const float* __restrict__ c1,
                                              float* __restrict__ Wt2f,
                                              float* __restrict__ b2f) {
    int tid = threadIdx.x;
    for (int idx = tid; idx < C_H * C_H; idx += 256) {
        int c = idx >> 7, o = idx & 127;
        Wt2f[idx] = W2[o * C_H + c] * a1[c];
    }
    if (tid < C_H) {
        float acc = b2[tid];
        for (int c = 0; c < C_H; ++c) acc += c1[c] * W2[tid * C_H + c];
        b2f[tid] = acc;
    }
}

// ---------------------------------------------------------------------------
// GEMM2 (in-place on d_out h region): z = h1 @ Wt2f + b2f; lrelu; partials.
// Each block only reads/writes its own 64 rows -> in-place is race-free.
// ---------------------------------------------------------------------------
__global__ __launch_bounds__(256) void k_gemm2(float* __restrict__ h,
                                               const float* __restrict__ Wt,
                                               const float* __restrict__ bias,
                                               float* __restrict__ ps,
                                               float* __restrict__ pq) {
    const int LDA = 132;
    __shared__ float A[64 * 132];
    int r0 = blockIdx.x * 64;
    int tid = threadIdx.x;

    const float* src = h + (size_t)r0 * C_H;
    for (int i = tid * 4; i < 64 * C_H; i += 1024) {
        float4 v = *(const float4*)&src[i];
        int r = i >> 7, c = i & 127;
        *(float4*)&A[r * LDA + c] = v;
    }
    __syncthreads();

    int tx = tid & 31, ty = tid >> 5;
    float acc[8][4];
    float4 bv = *(const float4*)&bias[tx * 4];
#pragma unroll
    for (int i = 0; i < 8; ++i) {
        acc[i][0] = bv.x; acc[i][1] = bv.y; acc[i][2] = bv.z; acc[i][3] = bv.w;
    }

    for (int c = 0; c < C_H; c += 4) {
        float4 w0v = *(const float4*)&Wt[(c + 0) * C_H + tx * 4];
        float4 w1v = *(const float4*)&Wt[(c + 1) * C_H + tx * 4];
        float4 w2v = *(const float4*)&Wt[(c + 2) * C_H + tx * 4];
        float4 w3v = *(const float4*)&Wt[(c + 3) * C_H + tx * 4];
#pragma unroll
        for (int i = 0; i < 8; ++i) {
            float4 av = *(const float4*)&A[(ty * 8 + i) * LDA + c];
            acc[i][0] += av.x * w0v.x + av.y * w1v.x + av.z * w2v.x + av.w * w3v.x;
            acc[i][1] += av.x * w0v.y + av.y * w1v.y + av.z * w2v.y + av.w * w3v.y;
            acc[i][2] += av.x * w0v.z + av.y * w1v.z + av.z * w2v.z + av.w * w3v.z;
            acc[i][3] += av.x * w0v.w + av.y * w1v.w + av.z * w2v.w + av.w * w3v.w;
        }
    }

    float pss[4] = {0.f, 0.f, 0.f, 0.f};
    float pqs[4] = {0.f, 0.f, 0.f, 0.f};
#pragma unroll
    for (int i = 0; i < 8; ++i) {
        int row = r0 + ty * 8 + i;
        float4 o;
        float z;
        z = acc[i][0]; z = z > 0.f ? z : SLOPE * z; o.x = z; pss[0] += z; pqs[0] += z * z;
        z = acc[i][1]; z = z > 0.f ? z : SLOPE * z; o.y = z; pss[1] += z; pqs[1] += z * z;
        z = acc[i][2]; z = z > 0.f ? z : SLOPE * z; o.z = z; pss[2] += z; pqs[2] += z * z;
        z = acc[i][3]; z = z > 0.f ? z : SLOPE * z; o.w = z; pss[3] += z; pqs[3] += z * z;
        *(float4*)&h[(size_t)row * C_H + tx * 4] = o;
    }

    __syncthreads();
    float* sS = A;
    float* sQ = A + 1024;
#pragma unroll
    for (int j = 0; j < 4; ++j) {
        sS[ty * 128 + tx * 4 + j] = pss[j];
        sQ[ty * 128 + tx * 4 + j] = pqs[j];
    }
    __syncthreads();
    if (tid < 128) {
        float s = 0.f, q = 0.f;
#pragma unroll
        for (int t = 0; t < 8; ++t) { s += sS[t * 128 + tid]; q += sQ[t * 128 + tid]; }
        ps[blockIdx.x * C_H + tid] = s;
        pq[blockIdx.x * C_H + tid] = q;
    }
}

// ---------------------------------------------------------------------------
// Final: BN2 affine in place on d_out h region; copy pos_skip & batch_skip.
// ---------------------------------------------------------------------------
__global__ __launch_bounds__(256) void k_final(float* __restrict__ out_h,
                                               const float* __restrict__ a2,
                                               const float* __restrict__ c2,
                                               const float* __restrict__ pos_skip,
                                               const int* __restrict__ batch_skip,
                                               float* __restrict__ out_pos,
                                               float* __restrict__ out_batch) {
    int gid = blockIdx.x * 256 + threadIdx.x;
    int stride = gridDim.x * 256;
    for (int i = gid; i < N_ROWS * C_H / 4; i += stride) {
        float4 v = *(float4*)&out_h[i * 4];
        int c = (i * 4) & 127;
        float4 av = *(const float4*)&a2[c];
        float4 cv = *(const float4*)&c2[c];
        v.x = v.x * av.x + cv.x;
        v.y = v.y * av.y + cv.y;
        v.z = v.z * av.z + cv.z;
        v.w = v.w * av.w + cv.w;
        *(float4*)&out_h[i * 4] = v;
    }
    for (int i = gid; i < N_ROWS * 3 / 4; i += stride) {
        *(float4*)&out_pos[i * 4] = *(const float4*)&pos_skip[i * 4];
    }
    for (int i = gid; i < N_ROWS; i += stride) {
        out_batch[i] = (float)batch_skip[i];
    }
}

// ---------------------------------------------------------------------------
extern "C" void kernel_launch(void* const* d_in, const int* in_sizes, int n_in,
                              void* d_out, int out_size, void* d_ws, size_t ws_size,
                              hipStream_t stream) {
    const float* x          = (const float*)d_in[0];
    const float* pos        = (const float*)d_in[1];
    const float* x_skip     = (const float*)d_in[3];
    const float* pos_skip   = (const float*)d_in[4];
    const int*   batch_skip = (const int*)d_in[5];
    const float* W1  = (const float*)d_in[6];
    const float* b1  = (const float*)d_in[7];
    const float* g1  = (const float*)d_in[8];
    const float* be1 = (const float*)d_in[9];
    const float* W2  = (const float*)d_in[10];
    const float* b2  = (const float*)d_in[11];
    const float* g2  = (const float*)d_in[12];
    const float* be2 = (const float*)d_in[13];

    float* out_h     = (float*)d_out;
    float* out_pos   = out_h + (size_t)N_ROWS * C_H;             // 8388608
    float* out_batch = out_pos + (size_t)N_ROWS * 3;             // +196608

    float* wsf = (float*)d_ws;
    int*   knn_idx = (int*)wsf;                     // 196608 ints
    float* knn_w   = wsf + 196608;                  // 196608 floats
    float* Wt1     = wsf + 393216;                  // 24576
    float* Wt2f    = Wt1 + 24576;                   // 16384
    float* b2f     = Wt2f + 16384;                  // 128
    float* p1s     = b2f + 128;                     // 131072
    float* p1q     = p1s + 131072;
    float* p2s     = p1q + 131072;
    float* p2q     = p2s + 131072;
    float* a1      = p2q + 131072;
    float* c1      = a1 + 128;
    float* a2      = c1 + 128;
    float* c2      = a2 + 128;

    k_prep<<<96, 256, 0, stream>>>(W1, Wt1);
    k_knn<<<256, 256, 0, stream>>>(pos, pos_skip, knn_idx, knn_w);
    k_gemm1<<<GEMM_BLOCKS, 256, 0, stream>>>(x, x_skip, knn_idx, knn_w, Wt1, b1,
                                             out_h, p1s, p1q);
    k_reduce<<<C_H, 256, 0, stream>>>(p1s, p1q, g1, be1, a1, c1);
    k_fold<<<1, 256, 0, stream>>>(W2, b2, a1, c1, Wt2f, b2f);
    k_gemm2<<<GEMM_BLOCKS, 256, 0, stream>>>(out_h, Wt2f, b2f, p2s, p2q);
    k_reduce<<<C_H, 256, 0, stream>>>(p2s, p2q, g2, be2, a2, c2);
    k_final<<<2048, 256, 0, stream>>>(out_h, a2, c2, pos_skip, batch_skip,
                                      out_pos, out_batch);
}

// Round 2
// 201.388 us; speedup vs baseline: 1.7728x; 1.7728x over previous
//
#include <hip/hip_runtime.h>
#include <math.h>

#define NB 8
#define N_SRC 2048
#define N_DST 8192
#define C_SRC 128
#define C_SKIP 64
#define C_IN 192
#define C_H 128
#define N_ROWS (NB * N_DST)   /* 65536 */
#define BN_EPS 1e-5f
#define SLOPE 0.01f
#define GEMM_BLOCKS (N_ROWS / 64)   /* 1024 */

// ---------------------------------------------------------------------------
// KNN v2: block = 64 dst points, 4 waves. Wave w scans src segment w (512
// points, wave-uniform LDS reads -> broadcast). 12-candidate merge in LDS.
// ---------------------------------------------------------------------------
__global__ __launch_bounds__(256) void k_knn(const float* __restrict__ pos,
                                             const float* __restrict__ pos_skip,
                                             int* __restrict__ knn_idx,
                                             float* __restrict__ knn_w) {
    __shared__ float4 sp[N_SRC];            // 32 KiB
    __shared__ float  cd[4][64][3];         // 3 KiB
    __shared__ int    ci[4][64][3];         // 3 KiB

    int cloud = blockIdx.x >> 7;            // 128 blocks of 64 dst per cloud
    int tile  = blockIdx.x & 127;
    const float* pb = pos + (size_t)cloud * N_SRC * 3;
    for (int i = threadIdx.x; i < N_SRC; i += 256) {
        sp[i] = make_float4(pb[i * 3 + 0], pb[i * 3 + 1], pb[i * 3 + 2], 0.f);
    }
    __syncthreads();

    int lane = threadIdx.x & 63, wv = threadIdx.x >> 6;
    int dst = cloud * N_DST + tile * 64 + lane;
    float px = pos_skip[dst * 3 + 0];
    float py = pos_skip[dst * 3 + 1];
    float pz = pos_skip[dst * 3 + 2];

    float d0 = 3.4e38f, d1 = 3.4e38f, d2 = 3.4e38f;
    int   i0 = 0, i1 = 0, i2 = 0;
    int jbase = wv << 9;                    // 512-point segment per wave
#pragma unroll 4
    for (int j = 0; j < 512; ++j) {
        float4 s = sp[jbase + j];           // wave-uniform addr -> broadcast
        float dx = px - s.x, dy = py - s.y, dz = pz - s.z;
        float d = dx * dx + dy * dy + dz * dz;
        if (d < d2) {
            int jj = jbase + j;
            if (d < d1) {
                d2 = d1; i2 = i1;
                if (d < d0) { d1 = d0; i1 = i0; d0 = d; i0 = jj; }
                else        { d1 = d;  i1 = jj; }
            } else { d2 = d; i2 = jj; }
        }
    }
    cd[wv][lane][0] = d0; cd[wv][lane][1] = d1; cd[wv][lane][2] = d2;
    ci[wv][lane][0] = i0; ci[wv][lane][1] = i1; ci[wv][lane][2] = i2;
    __syncthreads();

    if (threadIdx.x < 64) {
        int l = threadIdx.x;
        float e0 = 3.4e38f, e1 = 3.4e38f, e2 = 3.4e38f;
        int   m0 = 0, m1 = 0, m2 = 0;
#pragma unroll
        for (int s = 0; s < 4; ++s) {
#pragma unroll
            for (int t = 0; t < 3; ++t) {
                float d = cd[s][l][t];
                int  jj = ci[s][l][t];
                if (d < e2) {
                    if (d < e1) {
                        e2 = e1; m2 = m1;
                        if (d < e0) { e1 = e0; m1 = m0; e0 = d; m0 = jj; }
                        else        { e1 = d;  m1 = jj; }
                    } else { e2 = d; m2 = jj; }
                }
            }
        }
        float w0 = 1.f / fmaxf(e0, 1e-16f);
        float w1 = 1.f / fmaxf(e1, 1e-16f);
        float w2 = 1.f / fmaxf(e2, 1e-16f);
        float inv = 1.f / (w0 + w1 + w2);
        int row = cloud * N_DST + tile * 64 + l;
        knn_idx[row * 3 + 0] = m0;
        knn_idx[row * 3 + 1] = m1;
        knn_idx[row * 3 + 2] = m2;
        knn_w[row * 3 + 0] = w0 * inv;
        knn_w[row * 3 + 1] = w1 * inv;
        knn_w[row * 3 + 2] = w2 * inv;
    }
}

// ---------------------------------------------------------------------------
// Transpose W1 [128][192] -> Wt1 [192][128]
// ---------------------------------------------------------------------------
__global__ void k_prep(const float* __restrict__ W1, float* __restrict__ Wt1) {
    for (int idx = blockIdx.x * 256 + threadIdx.x; idx < C_IN * C_H;
         idx += gridDim.x * 256) {
        int c = idx >> 7, o = idx & 127;
        Wt1[idx] = W1[o * C_IN + c];
    }
}

// ---------------------------------------------------------------------------
// GEMM1: A-tile built in LDS from knn gather + x_skip; z = A @ Wt1 + b1;
// lrelu; write h1 -> out (d_out h region); per-block BN partials.
// ---------------------------------------------------------------------------
__global__ __launch_bounds__(256) void k_gemm1(const float* __restrict__ x,
                                               const float* __restrict__ x_skip,
                                               const int* __restrict__ knn_idx,
                                               const float* __restrict__ knn_w,
                                               const float* __restrict__ Wt,
                                               const float* __restrict__ bias,
                                               float* __restrict__ out,
                                               float* __restrict__ ps,
                                               float* __restrict__ pq) {
    const int LDA = 196;
    __shared__ float A[64 * 196];
    int r0 = blockIdx.x * 64;
    int cloud = r0 / N_DST;
    int tid = threadIdx.x;
    int lane = tid & 63, wid = tid >> 6;
    const float* xb = x + (size_t)cloud * N_SRC * C_SRC;

    for (int rr = wid * 16; rr < wid * 16 + 16; ++rr) {
        int row = r0 + rr;
        int j0 = knn_idx[row * 3 + 0];
        int j1 = knn_idx[row * 3 + 1];
        int j2 = knn_idx[row * 3 + 2];
        float w0 = knn_w[row * 3 + 0];
        float w1 = knn_w[row * 3 + 1];
        float w2 = knn_w[row * 3 + 2];
        const float* x0 = xb + (size_t)j0 * C_SRC;
        const float* x1 = xb + (size_t)j1 * C_SRC;
        const float* x2 = xb + (size_t)j2 * C_SRC;
        A[rr * LDA + lane]       = w0 * x0[lane]      + w1 * x1[lane]      + w2 * x2[lane];
        A[rr * LDA + 64 + lane]  = w0 * x0[64 + lane] + w1 * x1[64 + lane] + w2 * x2[64 + lane];
        A[rr * LDA + 128 + lane] = x_skip[(size_t)row * C_SKIP + lane];
    }
    __syncthreads();

    int tx = tid & 31, ty = tid >> 5;
    float acc[8][4];
    float4 bv = *(const float4*)&bias[tx * 4];
#pragma unroll
    for (int i = 0; i < 8; ++i) {
        acc[i][0] = bv.x; acc[i][1] = bv.y; acc[i][2] = bv.z; acc[i][3] = bv.w;
    }

    for (int c = 0; c < C_IN; c += 4) {
        float4 w0v = *(const float4*)&Wt[(c + 0) * C_H + tx * 4];
        float4 w1v = *(const float4*)&Wt[(c + 1) * C_H + tx * 4];
        float4 w2v = *(const float4*)&Wt[(c + 2) * C_H + tx * 4];
        float4 w3v = *(const float4*)&Wt[(c + 3) * C_H + tx * 4];
#pragma unroll
        for (int i = 0; i < 8; ++i) {
            float4 av = *(const float4*)&A[(ty * 8 + i) * LDA + c];
            acc[i][0] += av.x * w0v.x + av.y * w1v.x + av.z * w2v.x + av.w * w3v.x;
            acc[i][1] += av.x * w0v.y + av.y * w1v.y + av.z * w2v.y + av.w * w3v.y;
            acc[i][2] += av.x * w0v.z + av.y * w1v.z + av.z * w2v.z + av.w * w3v.z;
            acc[i][3] += av.x * w0v.w + av.y * w1v.w + av.z * w2v.w + av.w * w3v.w;
        }
    }

    float pss[4] = {0.f, 0.f, 0.f, 0.f};
    float pqs[4] = {0.f, 0.f, 0.f, 0.f};
#pragma unroll
    for (int i = 0; i < 8; ++i) {
        int row = r0 + ty * 8 + i;
        float4 o;
        float z;
        z = acc[i][0]; z = z > 0.f ? z : SLOPE * z; o.x = z; pss[0] += z; pqs[0] += z * z;
        z = acc[i][1]; z = z > 0.f ? z : SLOPE * z; o.y = z; pss[1] += z; pqs[1] += z * z;
        z = acc[i][2]; z = z > 0.f ? z : SLOPE * z; o.z = z; pss[2] += z; pqs[2] += z * z;
        z = acc[i][3]; z = z > 0.f ? z : SLOPE * z; o.w = z; pss[3] += z; pqs[3] += z * z;
        *(float4*)&out[(size_t)row * C_H + tx * 4] = o;
    }

    __syncthreads();   // done with A as GEMM tile
    float* sS = A;
    float* sQ = A + 1024;
#pragma unroll
    for (int j = 0; j < 4; ++j) {
        sS[ty * 128 + tx * 4 + j] = pss[j];
        sQ[ty * 128 + tx * 4 + j] = pqs[j];
    }
    __syncthreads();
    if (tid < 128) {
        float s = 0.f, q = 0.f;
#pragma unroll
        for (int t = 0; t < 8; ++t) { s += sS[t * 128 + tid]; q += sQ[t * 128 + tid]; }
        ps[blockIdx.x * C_H + tid] = s;
        pq[blockIdx.x * C_H + tid] = q;
    }
}

// ---------------------------------------------------------------------------
// Per-channel reduce of block partials -> BN affine (a = g*rsqrt, c = be-mean*a)
// ---------------------------------------------------------------------------
__global__ __launch_bounds__(256) void k_reduce(const float* __restrict__ ps,
                                                const float* __restrict__ pq,
                                                const float* __restrict__ g,
                                                const float* __restrict__ be,
                                                float* __restrict__ a_out,
                                                float* __restrict__ c_out) {
    int col = blockIdx.x;
    float s = 0.f, q = 0.f;
    for (int b = threadIdx.x; b < GEMM_BLOCKS; b += 256) {
        s += ps[b * C_H + col];
        q += pq[b * C_H + col];
    }
    for (int off = 32; off; off >>= 1) {
        s += __shfl_down(s, off);
        q += __shfl_down(q, off);
    }
    __shared__ float rs[4], rq[4];
    if ((threadIdx.x & 63) == 0) { rs[threadIdx.x >> 6] = s; rq[threadIdx.x >> 6] = q; }
    __syncthreads();
    if (threadIdx.x == 0) {
        s = rs[0] + rs[1] + rs[2] + rs[3];
        q = rq[0] + rq[1] + rq[2] + rq[3];
        float mean = s / (float)N_ROWS;
        float var  = q / (float)N_ROWS - mean * mean;
        float a = g[col] * rsqrtf(var + BN_EPS);
        a_out[col] = a;
        c_out[col] = be[col] - mean * a;
    }
}

// ---------------------------------------------------------------------------
// Fold BN1 affine into W2/b2:  Wt2f[c][o] = W2[o][c]*a1[c];  b2f = b2 + W2@c1
// ---------------------------------------------------------------------------
__global__ __launch_bounds__(256) void k_fold(const float* __restrict__ W2,
                                              const float* __restrict__ b2,
                                              const float* __restrict__ a1,
                                              const float* __restrict__ c1,
                                              float* __restrict__ Wt2f,
                                              float* __restrict__ b2f) {
    int tid = threadIdx.x;
    for (int idx = tid; idx < C_H * C_H; idx += 256) {
        int c = idx >> 7, o = idx & 127;
        Wt2f[idx] = W2[o * C_H + c] * a1[c];
    }
    if (tid < C_H) {
        float acc = b2[tid];
        for (int c = 0; c < C_H; ++c) acc += c1[c] * W2[tid * C_H + c];
        b2f[tid] = acc;
    }
}

// ---------------------------------------------------------------------------
// GEMM2 (in-place on d_out h region): z = h1 @ Wt2f + b2f; lrelu; partials.
// Each block only reads/writes its own 64 rows -> in-place is race-free.
// ---------------------------------------------------------------------------
__global__ __launch_bounds__(256) void k_gemm2(float* __restrict__ h,
                                               const float* __restrict__ Wt,
                                               const float* __restrict__ bias,
                                               float* __restrict__ ps,
                                               float* __restrict__ pq) {
    const int LDA = 132;
    __shared__ float A[64 * 132];
    int r0 = blockIdx.x * 64;
    int tid = threadIdx.x;

    const float* src = h + (size_t)r0 * C_H;
    for (int i = tid * 4; i < 64 * C_H; i += 1024) {
        float4 v = *(const float4*)&src[i];
        int r = i >> 7, c = i & 127;
        *(float4*)&A[r * LDA + c] = v;
    }
    __syncthreads();

    int tx = tid & 31, ty = tid >> 5;
    float acc[8][4];
    float4 bv = *(const float4*)&bias[tx * 4];
#pragma unroll
    for (int i = 0; i < 8; ++i) {
        acc[i][0] = bv.x; acc[i][1] = bv.y; acc[i][2] = bv.z; acc[i][3] = bv.w;
    }

    for (int c = 0; c < C_H; c += 4) {
        float4 w0v = *(const float4*)&Wt[(c + 0) * C_H + tx * 4];
        float4 w1v = *(const float4*)&Wt[(c + 1) * C_H + tx * 4];
        float4 w2v = *(const float4*)&Wt[(c + 2) * C_H + tx * 4];
        float4 w3v = *(const float4*)&Wt[(c + 3) * C_H + tx * 4];
#pragma unroll
        for (int i = 0; i < 8; ++i) {
            float4 av = *(const float4*)&A[(ty * 8 + i) * LDA + c];
            acc[i][0] += av.x * w0v.x + av.y * w1v.x + av.z * w2v.x + av.w * w3v.x;
            acc[i][1] += av.x * w0v.y + av.y * w1v.y + av.z * w2v.y + av.w * w3v.y;
            acc[i][2] += av.x * w0v.z + av.y * w1v.z + av.z * w2v.z + av.w * w3v.z;
            acc[i][3] += av.x * w0v.w + av.y * w1v.w + av.z * w2v.w + av.w * w3v.w;
        }
    }

    float pss[4] = {0.f, 0.f, 0.f, 0.f};
    float pqs[4] = {0.f, 0.f, 0.f, 0.f};
#pragma unroll
    for (int i = 0; i < 8; ++i) {
        int row = r0 + ty * 8 + i;
        float4 o;
        float z;
        z = acc[i][0]; z = z > 0.f ? z : SLOPE * z; o.x = z; pss[0] += z; pqs[0] += z * z;
        z = acc[i][1]; z = z > 0.f ? z : SLOPE * z; o.y = z; pss[1] += z; pqs[1] += z * z;
        z = acc[i][2]; z = z > 0.f ? z : SLOPE * z; o.z = z; pss[2] += z; pqs[2] += z * z;
        z = acc[i][3]; z = z > 0.f ? z : SLOPE * z; o.w = z; pss[3] += z; pqs[3] += z * z;
        *(float4*)&h[(size_t)row * C_H + tx * 4] = o;
    }

    __syncthreads();
    float* sS = A;
    float* sQ = A + 1024;
#pragma unroll
    for (int j = 0; j < 4; ++j) {
        sS[ty * 128 + tx * 4 + j] = pss[j];
        sQ[ty * 128 + tx * 4 + j] = pqs[j];
    }
    __syncthreads();
    if (tid < 128) {
        float s = 0.f, q = 0.f;
#pragma unroll
        for (int t = 0; t < 8; ++t) { s += sS[t * 128 + tid]; q += sQ[t * 128 + tid]; }
        ps[blockIdx.x * C_H + tid] = s;
        pq[blockIdx.x * C_H + tid] = q;
    }
}

// ---------------------------------------------------------------------------
// Final: BN2 affine in place on d_out h region; copy pos_skip & batch_skip.
// ---------------------------------------------------------------------------
__global__ __launch_bounds__(256) void k_final(float* __restrict__ out_h,
                                               const float* __restrict__ a2,
                                               const float* __restrict__ c2,
                                               const float* __restrict__ pos_skip,
                                               const int* __restrict__ batch_skip,
                                               float* __restrict__ out_pos,
                                               float* __restrict__ out_batch) {
    int gid = blockIdx.x * 256 + threadIdx.x;
    int stride = gridDim.x * 256;
    for (int i = gid; i < N_ROWS * C_H / 4; i += stride) {
        float4 v = *(float4*)&out_h[i * 4];
        int c = (i * 4) & 127;
        float4 av = *(const float4*)&a2[c];
        float4 cv = *(const float4*)&c2[c];
        v.x = v.x * av.x + cv.x;
        v.y = v.y * av.y + cv.y;
        v.z = v.z * av.z + cv.z;
        v.w = v.w * av.w + cv.w;
        *(float4*)&out_h[i * 4] = v;
    }
    for (int i = gid; i < N_ROWS * 3 / 4; i += stride) {
        *(float4*)&out_pos[i * 4] = *(const float4*)&pos_skip[i * 4];
    }
    for (int i = gid; i < N_ROWS; i += stride) {
        out_batch[i] = (float)batch_skip[i];
    }
}

// ---------------------------------------------------------------------------
extern "C" void kernel_launch(void* const* d_in, const int* in_sizes, int n_in,
                              void* d_out, int out_size, void* d_ws, size_t ws_size,
                              hipStream_t stream) {
    const float* x          = (const float*)d_in[0];
    const float* pos        = (const float*)d_in[1];
    const float* x_skip     = (const float*)d_in[3];
    const float* pos_skip   = (const float*)d_in[4];
    const int*   batch_skip = (const int*)d_in[5];
    const float* W1  = (const float*)d_in[6];
    const float* b1  = (const float*)d_in[7];
    const float* g1  = (const float*)d_in[8];
    const float* be1 = (const float*)d_in[9];
    const float* W2  = (const float*)d_in[10];
    const float* b2  = (const float*)d_in[11];
    const float* g2  = (const float*)d_in[12];
    const float* be2 = (const float*)d_in[13];

    float* out_h     = (float*)d_out;
    float* out_pos   = out_h + (size_t)N_ROWS * C_H;             // 8388608
    float* out_batch = out_pos + (size_t)N_ROWS * 3;             // +196608

    float* wsf = (float*)d_ws;
    int*   knn_idx = (int*)wsf;                     // 196608 ints
    float* knn_w   = wsf + 196608;                  // 196608 floats
    float* Wt1     = wsf + 393216;                  // 24576
    float* Wt2f    = Wt1 + 24576;                   // 16384
    float* b2f     = Wt2f + 16384;                  // 128
    float* p1s     = b2f + 128;                     // 131072
    float* p1q     = p1s + 131072;
    float* p2s     = p1q + 131072;
    float* p2q     = p2s + 131072;
    float* a1      = p2q + 131072;
    float* c1      = a1 + 128;
    float* a2      = c1 + 128;
    float* c2      = a2 + 128;

    k_prep<<<96, 256, 0, stream>>>(W1, Wt1);
    k_knn<<<NB * (N_DST / 64), 256, 0, stream>>>(pos, pos_skip, knn_idx, knn_w);
    k_gemm1<<<GEMM_BLOCKS, 256, 0, stream>>>(x, x_skip, knn_idx, knn_w, Wt1, b1,
                                             out_h, p1s, p1q);
    k_reduce<<<C_H, 256, 0, stream>>>(p1s, p1q, g1, be1, a1, c1);
    k_fold<<<1, 256, 0, stream>>>(W2, b2, a1, c1, Wt2f, b2f);
    k_gemm2<<<GEMM_BLOCKS, 256, 0, stream>>>(out_h, Wt2f, b2f, p2s, p2q);
    k_reduce<<<C_H, 256, 0, stream>>>(p2s, p2q, g2, be2, a2, c2);
    k_final<<<2048, 256, 0, stream>>>(out_h, a2, c2, pos_skip, batch_skip,
                                      out_pos, out_batch);
}

// Round 3
// 172.335 us; speedup vs baseline: 2.0717x; 1.1686x over previous
//
#include <hip/hip_runtime.h>
#include <math.h>

#define NB 8
#define N_SRC 2048
#define N_DST 8192
#define C_SRC 128
#define C_SKIP 64
#define C_IN 192
#define C_H 128
#define N_ROWS (NB * N_DST)   /* 65536 */
#define BN_EPS 1e-5f
#define SLOPE 0.01f
#define GEMM_BLOCKS (N_ROWS / 64)   /* 1024 */

using short8 = __attribute__((ext_vector_type(8))) short;
using f32x4  = __attribute__((ext_vector_type(4))) float;
using ushort4v = __attribute__((ext_vector_type(4))) unsigned short;

static __device__ __forceinline__ unsigned short f2bf(float f) {
    unsigned u = __builtin_bit_cast(unsigned, f);
    u = u + 0x7FFFu + ((u >> 16) & 1u);   // round-to-nearest-even
    return (unsigned short)(u >> 16);
}

// ---------------------------------------------------------------------------
// KNN: block = 64 dst points, 4 waves; wave scans a 512-pt src segment.
// ---------------------------------------------------------------------------
__global__ __launch_bounds__(256) void k_knn(const float* __restrict__ pos,
                                             const float* __restrict__ pos_skip,
                                             int* __restrict__ knn_idx,
                                             float* __restrict__ knn_w) {
    __shared__ float4 sp[N_SRC];
    __shared__ float  cd[4][64][3];
    __shared__ int    ci[4][64][3];

    int cloud = blockIdx.x >> 7;
    int tile  = blockIdx.x & 127;
    const float* pb = pos + (size_t)cloud * N_SRC * 3;
    for (int i = threadIdx.x; i < N_SRC; i += 256) {
        sp[i] = make_float4(pb[i * 3 + 0], pb[i * 3 + 1], pb[i * 3 + 2], 0.f);
    }
    __syncthreads();

    int lane = threadIdx.x & 63, wv = threadIdx.x >> 6;
    int dst = cloud * N_DST + tile * 64 + lane;
    float px = pos_skip[dst * 3 + 0];
    float py = pos_skip[dst * 3 + 1];
    float pz = pos_skip[dst * 3 + 2];

    float d0 = 3.4e38f, d1 = 3.4e38f, d2 = 3.4e38f;
    int   i0 = 0, i1 = 0, i2 = 0;
    int jbase = wv << 9;
#pragma unroll 4
    for (int j = 0; j < 512; ++j) {
        float4 s = sp[jbase + j];
        float dx = px - s.x, dy = py - s.y, dz = pz - s.z;
        float d = dx * dx + dy * dy + dz * dz;
        if (d < d2) {
            int jj = jbase + j;
            if (d < d1) {
                d2 = d1; i2 = i1;
                if (d < d0) { d1 = d0; i1 = i0; d0 = d; i0 = jj; }
                else        { d1 = d;  i1 = jj; }
            } else { d2 = d; i2 = jj; }
        }
    }
    cd[wv][lane][0] = d0; cd[wv][lane][1] = d1; cd[wv][lane][2] = d2;
    ci[wv][lane][0] = i0; ci[wv][lane][1] = i1; ci[wv][lane][2] = i2;
    __syncthreads();

    if (threadIdx.x < 64) {
        int l = threadIdx.x;
        float e0 = 3.4e38f, e1 = 3.4e38f, e2 = 3.4e38f;
        int   m0 = 0, m1 = 0, m2 = 0;
#pragma unroll
        for (int s = 0; s < 4; ++s) {
#pragma unroll
            for (int t = 0; t < 3; ++t) {
                float d = cd[s][l][t];
                int  jj = ci[s][l][t];
                if (d < e2) {
                    if (d < e1) {
                        e2 = e1; m2 = m1;
                        if (d < e0) { e1 = e0; m1 = m0; e0 = d; m0 = jj; }
                        else        { e1 = d;  m1 = jj; }
                    } else { e2 = d; m2 = jj; }
                }
            }
        }
        float w0 = 1.f / fmaxf(e0, 1e-16f);
        float w1 = 1.f / fmaxf(e1, 1e-16f);
        float w2 = 1.f / fmaxf(e2, 1e-16f);
        float inv = 1.f / (w0 + w1 + w2);
        int row = cloud * N_DST + tile * 64 + l;
        knn_idx[row * 3 + 0] = m0;
        knn_idx[row * 3 + 1] = m1;
        knn_idx[row * 3 + 2] = m2;
        knn_w[row * 3 + 0] = w0 * inv;
        knn_w[row * 3 + 1] = w1 * inv;
        knn_w[row * 3 + 2] = w2 * inv;
    }
}

// ---------------------------------------------------------------------------
// Prep: W1 fp32 [128][192] -> bf16 [128][192] (same layout, K-contiguous)
// ---------------------------------------------------------------------------
__global__ void k_prep(const float* __restrict__ W1,
                       unsigned short* __restrict__ W1bf) {
    for (int idx = blockIdx.x * 256 + threadIdx.x; idx < C_H * C_IN;
         idx += gridDim.x * 256) {
        W1bf[idx] = f2bf(W1[idx]);
    }
}

// ---------------------------------------------------------------------------
// GEMM1 (MFMA bf16): A-tile gathered into LDS bf16; B-frags from global
// (W1bf is [col][k] K-contiguous). h1 = lrelu(A@W1^T + b1) -> out fp32.
// ---------------------------------------------------------------------------
__global__ __launch_bounds__(256) void k_gemm1(const float* __restrict__ x,
                                               const float* __restrict__ x_skip,
                                               const int* __restrict__ knn_idx,
                                               const float* __restrict__ knn_w,
                                               const unsigned short* __restrict__ Wbf,
                                               const float* __restrict__ bias,
                                               float* __restrict__ out,
                                               float* __restrict__ ps,
                                               float* __restrict__ pq) {
    __shared__ __align__(16) unsigned short Ash[64][200];
    __shared__ float sS[4][128];
    __shared__ float sQ[4][128];

    int r0 = blockIdx.x * 64;
    int cloud = r0 / N_DST;
    int tid = threadIdx.x;
    int l = tid & 63, w = tid >> 6;
    const float* xb = x + (size_t)cloud * N_SRC * C_SRC;

    // --- stage A tile (gather + interp), fp32 math -> bf16 LDS
    for (int rr = w * 16; rr < w * 16 + 16; ++rr) {
        int row = r0 + rr;
        int j0 = knn_idx[row * 3 + 0];
        int j1 = knn_idx[row * 3 + 1];
        int j2 = knn_idx[row * 3 + 2];
        float w0 = knn_w[row * 3 + 0];
        float w1 = knn_w[row * 3 + 1];
        float w2 = knn_w[row * 3 + 2];
        const float* x0 = xb + (size_t)j0 * C_SRC;
        const float* x1 = xb + (size_t)j1 * C_SRC;
        const float* x2 = xb + (size_t)j2 * C_SRC;
        Ash[rr][l]       = f2bf(w0 * x0[l]      + w1 * x1[l]      + w2 * x2[l]);
        Ash[rr][64 + l]  = f2bf(w0 * x0[64 + l] + w1 * x1[64 + l] + w2 * x2[64 + l]);
        Ash[rr][128 + l] = f2bf(x_skip[(size_t)row * C_SKIP + l]);
    }
    __syncthreads();

    // --- MFMA: wave w owns rows [w*16, w*16+16), all 128 cols (8 tiles)
    int cl = l & 15, kh = l >> 4;           // col-in-tile / k-quarter
    f32x4 acc[8];
#pragma unroll
    for (int n = 0; n < 8; ++n) {
        float bv = bias[n * 16 + cl];
        acc[n][0] = bv; acc[n][1] = bv; acc[n][2] = bv; acc[n][3] = bv;
    }
    const unsigned short* wb = Wbf + (size_t)cl * C_IN + kh * 8;
    for (int kt = 0; kt < 6; ++kt) {
        short8 af = *(const short8*)&Ash[w * 16 + cl][kt * 32 + kh * 8];
#pragma unroll
        for (int n = 0; n < 8; ++n) {
            short8 bf = *(const short8*)(wb + (size_t)n * 16 * C_IN + kt * 32);
            acc[n] = __builtin_amdgcn_mfma_f32_16x16x32_bf16(af, bf, acc[n], 0, 0, 0);
        }
    }

    // --- epilogue: lrelu + store + per-column partial sums
    float pss[8], pqs[8];
#pragma unroll
    for (int n = 0; n < 8; ++n) {
        float s = 0.f, q = 0.f;
        int col = n * 16 + cl;
#pragma unroll
        for (int j = 0; j < 4; ++j) {
            int row = r0 + w * 16 + kh * 4 + j;
            float z = acc[n][j];
            z = z > 0.f ? z : SLOPE * z;
            out[(size_t)row * C_H + col] = z;
            s += z; q += z * z;
        }
        s += __shfl_xor(s, 16); s += __shfl_xor(s, 32);
        q += __shfl_xor(q, 16); q += __shfl_xor(q, 32);
        pss[n] = s; pqs[n] = q;
    }
    if (l < 16) {
#pragma unroll
        for (int n = 0; n < 8; ++n) {
            sS[w][n * 16 + l] = pss[n];
            sQ[w][n * 16 + l] = pqs[n];
        }
    }
    __syncthreads();
    if (tid < 128) {
        float s = sS[0][tid] + sS[1][tid] + sS[2][tid] + sS[3][tid];
        float q = sQ[0][tid] + sQ[1][tid] + sQ[2][tid] + sQ[3][tid];
        ps[blockIdx.x * C_H + tid] = s;
        pq[blockIdx.x * C_H + tid] = q;
    }
}

// ---------------------------------------------------------------------------
// Per-channel reduce of block partials -> BN affine
// ---------------------------------------------------------------------------
__global__ __launch_bounds__(256) void k_reduce(const float* __restrict__ ps,
                                                const float* __restrict__ pq,
                                                const float* __restrict__ g,
                                                const float* __restrict__ be,
                                                float* __restrict__ a_out,
                                                float* __restrict__ c_out) {
    int col = blockIdx.x;
    float s = 0.f, q = 0.f;
    for (int b = threadIdx.x; b < GEMM_BLOCKS; b += 256) {
        s += ps[b * C_H + col];
        q += pq[b * C_H + col];
    }
    for (int off = 32; off; off >>= 1) {
        s += __shfl_down(s, off);
        q += __shfl_down(q, off);
    }
    __shared__ float rs[4], rq[4];
    if ((threadIdx.x & 63) == 0) { rs[threadIdx.x >> 6] = s; rq[threadIdx.x >> 6] = q; }
    __syncthreads();
    if (threadIdx.x == 0) {
        s = rs[0] + rs[1] + rs[2] + rs[3];
        q = rq[0] + rq[1] + rq[2] + rq[3];
        float mean = s / (float)N_ROWS;
        float var  = q / (float)N_ROWS - mean * mean;
        float a = g[col] * rsqrtf(var + BN_EPS);
        a_out[col] = a;
        c_out[col] = be[col] - mean * a;
    }
}

// ---------------------------------------------------------------------------
// Fold BN1 into W2/b2:  W2f[o][c] = bf16(W2[o][c]*a1[c]);  b2f = b2 + W2@c1
// ---------------------------------------------------------------------------
__global__ __launch_bounds__(256) void k_fold(const float* __restrict__ W2,
                                              const float* __restrict__ b2,
                                              const float* __restrict__ a1,
                                              const float* __restrict__ c1,
                                              unsigned short* __restrict__ W2f,
                                              float* __restrict__ b2f) {
    int tid = threadIdx.x;
    for (int idx = tid; idx < C_H * C_H; idx += 256) {
        int o = idx >> 7, c = idx & 127;
        W2f[idx] = f2bf(W2[o * C_H + c] * a1[c]);
    }
    if (tid < C_H) {
        float acc = b2[tid];
        for (int c = 0; c < C_H; ++c) acc += c1[c] * W2[tid * C_H + c];
        b2f[tid] = acc;
    }
}

// ---------------------------------------------------------------------------
// GEMM2 (MFMA bf16, in-place on d_out h region): h2 = lrelu(h1@W2f^T + b2f)
// ---------------------------------------------------------------------------
__global__ __launch_bounds__(256) void k_gemm2(float* __restrict__ h,
                                               const unsigned short* __restrict__ Wbf,
                                               const float* __restrict__ b2f,
                                               float* __restrict__ ps,
                                               float* __restrict__ pq) {
    __shared__ __align__(16) unsigned short Ash[64][136];
    __shared__ float sS[4][128];
    __shared__ float sQ[4][128];

    int r0 = blockIdx.x * 64;
    int tid = threadIdx.x;
    int l = tid & 63, w = tid >> 6;

    // --- stage A tile: read h1 fp32 (coalesced float4) -> bf16 LDS
    const float* src = h + (size_t)r0 * C_H;
    for (int i = tid * 4; i < 64 * C_H; i += 1024) {
        float4 v = *(const float4*)&src[i];
        int r = i >> 7, c = i & 127;
        ushort4v u;
        u.x = f2bf(v.x); u.y = f2bf(v.y); u.z = f2bf(v.z); u.w = f2bf(v.w);
        *(ushort4v*)&Ash[r][c] = u;
    }
    __syncthreads();

    int cl = l & 15, kh = l >> 4;
    f32x4 acc[8];
#pragma unroll
    for (int n = 0; n < 8; ++n) {
        float bv = b2f[n * 16 + cl];
        acc[n][0] = bv; acc[n][1] = bv; acc[n][2] = bv; acc[n][3] = bv;
    }
    const unsigned short* wb = Wbf + (size_t)cl * C_H + kh * 8;
    for (int kt = 0; kt < 4; ++kt) {
        short8 af = *(const short8*)&Ash[w * 16 + cl][kt * 32 + kh * 8];
#pragma unroll
        for (int n = 0; n < 8; ++n) {
            short8 bf = *(const short8*)(wb + (size_t)n * 16 * C_H + kt * 32);
            acc[n] = __builtin_amdgcn_mfma_f32_16x16x32_bf16(af, bf, acc[n], 0, 0, 0);
        }
    }

    float pss[8], pqs[8];
#pragma unroll
    for (int n = 0; n < 8; ++n) {
        float s = 0.f, q = 0.f;
        int col = n * 16 + cl;
#pragma unroll
        for (int j = 0; j < 4; ++j) {
            int row = r0 + w * 16 + kh * 4 + j;
            float z = acc[n][j];
            z = z > 0.f ? z : SLOPE * z;
            h[(size_t)row * C_H + col] = z;
            s += z; q += z * z;
        }
        s += __shfl_xor(s, 16); s += __shfl_xor(s, 32);
        q += __shfl_xor(q, 16); q += __shfl_xor(q, 32);
        pss[n] = s; pqs[n] = q;
    }
    if (l < 16) {
#pragma unroll
        for (int n = 0; n < 8; ++n) {
            sS[w][n * 16 + l] = pss[n];
            sQ[w][n * 16 + l] = pqs[n];
        }
    }
    __syncthreads();
    if (tid < 128) {
        float s = sS[0][tid] + sS[1][tid] + sS[2][tid] + sS[3][tid];
        float q = sQ[0][tid] + sQ[1][tid] + sQ[2][tid] + sQ[3][tid];
        ps[blockIdx.x * C_H + tid] = s;
        pq[blockIdx.x * C_H + tid] = q;
    }
}

// ---------------------------------------------------------------------------
// Final: BN2 affine in place; copy pos_skip & batch_skip.
// ---------------------------------------------------------------------------
__global__ __launch_bounds__(256) void k_final(float* __restrict__ out_h,
                                               const float* __restrict__ a2,
                                               const float* __restrict__ c2,
                                               const float* __restrict__ pos_skip,
                                               const int* __restrict__ batch_skip,
                                               float* __restrict__ out_pos,
                                               float* __restrict__ out_batch) {
    int gid = blockIdx.x * 256 + threadIdx.x;
    int stride = gridDim.x * 256;
    for (int i = gid; i < N_ROWS * C_H / 4; i += stride) {
        float4 v = *(float4*)&out_h[i * 4];
        int c = (i * 4) & 127;
        float4 av = *(const float4*)&a2[c];
        float4 cv = *(const float4*)&c2[c];
        v.x = v.x * av.x + cv.x;
        v.y = v.y * av.y + cv.y;
        v.z = v.z * av.z + cv.z;
        v.w = v.w * av.w + cv.w;
        *(float4*)&out_h[i * 4] = v;
    }
    for (int i = gid; i < N_ROWS * 3 / 4; i += stride) {
        *(float4*)&out_pos[i * 4] = *(const float4*)&pos_skip[i * 4];
    }
    for (int i = gid; i < N_ROWS; i += stride) {
        out_batch[i] = (float)batch_skip[i];
    }
}

// ---------------------------------------------------------------------------
extern "C" void kernel_launch(void* const* d_in, const int* in_sizes, int n_in,
                              void* d_out, int out_size, void* d_ws, size_t ws_size,
                              hipStream_t stream) {
    const float* x          = (const float*)d_in[0];
    const float* pos        = (const float*)d_in[1];
    const float* x_skip     = (const float*)d_in[3];
    const float* pos_skip   = (const float*)d_in[4];
    const int*   batch_skip = (const int*)d_in[5];
    const float* W1  = (const float*)d_in[6];
    const float* b1  = (const float*)d_in[7];
    const float* g1  = (const float*)d_in[8];
    const float* be1 = (const float*)d_in[9];
    const float* W2  = (const float*)d_in[10];
    const float* b2  = (const float*)d_in[11];
    const float* g2  = (const float*)d_in[12];
    const float* be2 = (const float*)d_in[13];

    float* out_h     = (float*)d_out;
    float* out_pos   = out_h + (size_t)N_ROWS * C_H;
    float* out_batch = out_pos + (size_t)N_ROWS * 3;

    float* wsf = (float*)d_ws;
    int*   knn_idx = (int*)wsf;                     // 196608 ints
    float* knn_w   = wsf + 196608;                  // 196608 floats
    unsigned short* W1bf = (unsigned short*)(wsf + 393216);  // 24576 ushorts (12288 f)
    unsigned short* W2f  = (unsigned short*)(wsf + 405504);  // 16384 ushorts (8192 f)
    float* b2f     = wsf + 413696;                  // 128
    float* p1s     = b2f + 128;                     // 131072
    float* p1q     = p1s + 131072;
    float* p2s     = p1q + 131072;
    float* p2q     = p2s + 131072;
    float* a1      = p2q + 131072;
    float* c1      = a1 + 128;
    float* a2      = c1 + 128;
    float* c2      = a2 + 128;

    k_prep<<<96, 256, 0, stream>>>(W1, W1bf);
    k_knn<<<NB * (N_DST / 64), 256, 0, stream>>>(pos, pos_skip, knn_idx, knn_w);
    k_gemm1<<<GEMM_BLOCKS, 256, 0, stream>>>(x, x_skip, knn_idx, knn_w, W1bf, b1,
                                             out_h, p1s, p1q);
    k_reduce<<<C_H, 256, 0, stream>>>(p1s, p1q, g1, be1, a1, c1);
    k_fold<<<1, 256, 0, stream>>>(W2, b2, a1, c1, W2f, b2f);
    k_gemm2<<<GEMM_BLOCKS, 256, 0, stream>>>(out_h, W2f, b2f, p2s, p2q);
    k_reduce<<<C_H, 256, 0, stream>>>(p2s, p2q, g2, be2, a2, c2);
    k_final<<<2048, 256, 0, stream>>>(out_h, a2, c2, pos_skip, batch_skip,
                                      out_pos, out_batch);
}

// Round 4
// 161.821 us; speedup vs baseline: 2.2063x; 1.0650x over previous
//
#include <hip/hip_runtime.h>
#include <math.h>

#define NB 8
#define N_SRC 2048
#define N_DST 8192
#define C_SRC 128
#define C_SKIP 64
#define C_IN 192
#define C_H 128
#define N_ROWS (NB * N_DST)   /* 65536 */
#define BN_EPS 1e-5f
#define SLOPE 0.01f
#define GEMM_BLOCKS (N_ROWS / 64)   /* 1024 */

using short8 = __attribute__((ext_vector_type(8))) short;
using f32x4  = __attribute__((ext_vector_type(4))) float;

static __device__ __forceinline__ unsigned short f2bf(float f) {
    unsigned u = __builtin_bit_cast(unsigned, f);
    u = u + 0x7FFFu + ((u >> 16) & 1u);   // round-to-nearest-even
    return (unsigned short)(u >> 16);
}

// ---------------------------------------------------------------------------
// Prep: W1 fp32 -> bf16 (same [out][in] layout); pos -> padded float4 array
// ---------------------------------------------------------------------------
__global__ __launch_bounds__(256) void k_prep(const float* __restrict__ W1,
                                              unsigned short* __restrict__ W1bf,
                                              const float* __restrict__ pos,
                                              float4* __restrict__ pos4) {
    int gid = blockIdx.x * 256 + threadIdx.x;
    int stride = gridDim.x * 256;
    for (int i = gid; i < C_H * C_IN; i += stride) W1bf[i] = f2bf(W1[i]);
    for (int p = gid; p < NB * N_SRC; p += stride) {
        pos4[p] = make_float4(pos[p * 3 + 0], pos[p * 3 + 1], pos[p * 3 + 2], 0.f);
    }
}

// ---------------------------------------------------------------------------
// Fused KNN + GEMM1. Block = 64 dst rows, 4 waves.
// Phase A: branchless top-3 scan over per-wave 512-pt segment (s_load src pts).
// Phase B: merge 12 candidates -> LDS; gather+interp A-tile bf16; MFMA;
//          lrelu; h1 fp32 -> out; BN1 partial sums.
// ---------------------------------------------------------------------------
__global__ __launch_bounds__(256) void k_fused1(const float4* __restrict__ pos4,
                                                const float* __restrict__ pos_skip,
                                                const float* __restrict__ x,
                                                const float* __restrict__ x_skip,
                                                const unsigned short* __restrict__ Wbf,
                                                const float* __restrict__ bias,
                                                float* __restrict__ out,
                                                float* __restrict__ ps,
                                                float* __restrict__ pq) {
    __shared__ __align__(16) unsigned short Ash[64][200];   // 25600 B (cd/ci overlay)
    __shared__ float sS[4][128];
    __shared__ float sQ[4][128];
    __shared__ int   midx[64][3];
    __shared__ float mw[64][3];

    float* cd = (float*)&Ash[0][0];                  // [4][64][3] floats, 3072 B
    int*   ci = (int*)((char*)&Ash[0][0] + 3072);    // [4][64][3] ints,   3072 B

    int tid = threadIdx.x;
    int l = tid & 63;
    int w = __builtin_amdgcn_readfirstlane(tid >> 6);  // wave id, provably uniform
    int cloud = blockIdx.x >> 7;
    int r0 = blockIdx.x * 64;

    // ---------------- Phase A: KNN scan (branchless) ----------------
    int dst = r0 + l;
    float px = pos_skip[dst * 3 + 0];
    float py = pos_skip[dst * 3 + 1];
    float pz = pos_skip[dst * 3 + 2];

    const float4* __restrict__ pw = pos4 + (cloud << 11) + (w << 9);
    float d0 = 3.4e38f, d1 = 3.4e38f, d2 = 3.4e38f;
    int   i0 = 0, i1 = 0, i2 = 0;
#pragma unroll 8
    for (int j = 0; j < 512; ++j) {
        float4 s = pw[j];                        // wave-uniform -> s_load_dwordx4
        float dx = px - s.x, dy = py - s.y, dz = pz - s.z;
        float d = fmaf(dx, dx, fmaf(dy, dy, dz * dz));
        bool c0 = d < d0, c1 = d < d1, c2 = d < d2;
        int jj = (w << 9) + j;
        i2 = c1 ? i1 : (c2 ? jj : i2);
        i1 = c0 ? i0 : (c1 ? jj : i1);
        i0 = c0 ? jj : i0;
        d2 = __builtin_amdgcn_fmed3f(d, d1, d2);
        d1 = __builtin_amdgcn_fmed3f(d, d0, d1);
        d0 = fminf(d0, d);
    }
    cd[(w * 64 + l) * 3 + 0] = d0; ci[(w * 64 + l) * 3 + 0] = i0;
    cd[(w * 64 + l) * 3 + 1] = d1; ci[(w * 64 + l) * 3 + 1] = i1;
    cd[(w * 64 + l) * 3 + 2] = d2; ci[(w * 64 + l) * 3 + 2] = i2;
    __syncthreads();

    // ---------------- merge 12 candidates per dst ----------------
    if (tid < 64) {
        float e0 = 3.4e38f, e1 = 3.4e38f, e2 = 3.4e38f;
        int   m0 = 0, m1 = 0, m2 = 0;
#pragma unroll
        for (int s = 0; s < 4; ++s) {
#pragma unroll
            for (int t = 0; t < 3; ++t) {
                float d = cd[(s * 64 + tid) * 3 + t];
                int  jj = ci[(s * 64 + tid) * 3 + t];
                bool c0 = d < e0, c1 = d < e1, c2 = d < e2;
                m2 = c1 ? m1 : (c2 ? jj : m2);
                m1 = c0 ? m0 : (c1 ? jj : m1);
                m0 = c0 ? jj : m0;
                e2 = __builtin_amdgcn_fmed3f(d, e1, e2);
                e1 = __builtin_amdgcn_fmed3f(d, e0, e1);
                e0 = fminf(e0, d);
            }
        }
        float w0 = 1.f / fmaxf(e0, 1e-16f);
        float w1 = 1.f / fmaxf(e1, 1e-16f);
        float w2 = 1.f / fmaxf(e2, 1e-16f);
        float inv = 1.f / (w0 + w1 + w2);
        midx[tid][0] = m0; midx[tid][1] = m1; midx[tid][2] = m2;
        mw[tid][0] = w0 * inv; mw[tid][1] = w1 * inv; mw[tid][2] = w2 * inv;
    }
    __syncthreads();

    // ---------------- Phase B: gather + interp -> bf16 A tile ----------------
    const float* xb = x + (size_t)cloud * N_SRC * C_SRC;
    for (int rr = w * 16; rr < w * 16 + 16; ++rr) {
        int j0 = midx[rr][0], j1 = midx[rr][1], j2 = midx[rr][2];
        float w0 = mw[rr][0], w1 = mw[rr][1], w2 = mw[rr][2];
        const float2* x0v = (const float2*)(xb + (size_t)j0 * C_SRC);
        const float2* x1v = (const float2*)(xb + (size_t)j1 * C_SRC);
        const float2* x2v = (const float2*)(xb + (size_t)j2 * C_SRC);
        float2 a = x0v[l], b = x1v[l], c = x2v[l];
        float v0 = w0 * a.x + w1 * b.x + w2 * c.x;
        float v1 = w0 * a.y + w1 * b.y + w2 * c.y;
        ((unsigned*)&Ash[rr][0])[l] = (unsigned)f2bf(v0) | ((unsigned)f2bf(v1) << 16);
        Ash[rr][128 + l] = f2bf(x_skip[(size_t)(r0 + rr) * C_SKIP + l]);
    }
    // waves read only their own 16-row slab -> no barrier needed

    // ---------------- MFMA ----------------
    int cl = l & 15, kh = l >> 4;
    f32x4 acc[8];
#pragma unroll
    for (int n = 0; n < 8; ++n) {
        float bv = bias[n * 16 + cl];
        acc[n][0] = bv; acc[n][1] = bv; acc[n][2] = bv; acc[n][3] = bv;
    }
    const unsigned short* wb = Wbf + (size_t)cl * C_IN + kh * 8;
    for (int kt = 0; kt < 6; ++kt) {
        short8 af = *(const short8*)&Ash[w * 16 + cl][kt * 32 + kh * 8];
#pragma unroll
        for (int n = 0; n < 8; ++n) {
            short8 bf = *(const short8*)(wb + (size_t)n * 16 * C_IN + kt * 32);
            acc[n] = __builtin_amdgcn_mfma_f32_16x16x32_bf16(af, bf, acc[n], 0, 0, 0);
        }
    }

    // ---------------- epilogue: lrelu + store fp32 + BN1 partials ----------------
    float pss[8], pqs[8];
#pragma unroll
    for (int n = 0; n < 8; ++n) {
        float s = 0.f, q = 0.f;
        int col = n * 16 + cl;
#pragma unroll
        for (int j = 0; j < 4; ++j) {
            int row = r0 + w * 16 + kh * 4 + j;
            float z = acc[n][j];
            z = z > 0.f ? z : SLOPE * z;
            out[(size_t)row * C_H + col] = z;
            s += z; q += z * z;
        }
        s += __shfl_xor(s, 16); s += __shfl_xor(s, 32);
        q += __shfl_xor(q, 16); q += __shfl_xor(q, 32);
        pss[n] = s; pqs[n] = q;
    }
    if (l < 16) {
#pragma unroll
        for (int n = 0; n < 8; ++n) {
            sS[w][n * 16 + l] = pss[n];
            sQ[w][n * 16 + l] = pqs[n];
        }
    }
    __syncthreads();
    if (tid < 128) {
        float s = sS[0][tid] + sS[1][tid] + sS[2][tid] + sS[3][tid];
        float q = sQ[0][tid] + sQ[1][tid] + sQ[2][tid] + sQ[3][tid];
        ps[blockIdx.x * C_H + tid] = s;
        pq[blockIdx.x * C_H + tid] = q;
    }
}

// ---------------------------------------------------------------------------
// Per-channel reduce of block partials -> BN affine
// ---------------------------------------------------------------------------
__global__ __launch_bounds__(256) void k_reduce(const float* __restrict__ ps,
                                                const float* __restrict__ pq,
                                                const float* __restrict__ g,
                                                const float* __restrict__ be,
                                                float* __restrict__ a_out,
                                                float* __restrict__ c_out) {
    int col = blockIdx.x;
    float s = 0.f, q = 0.f;
    for (int b = threadIdx.x; b < GEMM_BLOCKS; b += 256) {
        s += ps[b * C_H + col];
        q += pq[b * C_H + col];
    }
    for (int off = 32; off; off >>= 1) {
        s += __shfl_down(s, off);
        q += __shfl_down(q, off);
    }
    __shared__ float rs[4], rq[4];
    if ((threadIdx.x & 63) == 0) { rs[threadIdx.x >> 6] = s; rq[threadIdx.x >> 6] = q; }
    __syncthreads();
    if (threadIdx.x == 0) {
        s = rs[0] + rs[1] + rs[2] + rs[3];
        q = rq[0] + rq[1] + rq[2] + rq[3];
        float mean = s / (float)N_ROWS;
        float var  = q / (float)N_ROWS - mean * mean;
        float a = g[col] * rsqrtf(var + BN_EPS);
        a_out[col] = a;
        c_out[col] = be[col] - mean * a;
    }
}

// ---------------------------------------------------------------------------
// Fold BN1 into W2/b2:  W2f[o][c] = bf16(W2[o][c]*a1[c]);  b2f = b2 + W2@c1
// ---------------------------------------------------------------------------
__global__ __launch_bounds__(256) void k_fold(const float* __restrict__ W2,
                                              const float* __restrict__ b2,
                                              const float* __restrict__ a1,
                                              const float* __restrict__ c1,
                                              unsigned short* __restrict__ W2f,
                                              float* __restrict__ b2f) {
    int tid = threadIdx.x;
    for (int idx = tid; idx < C_H * C_H; idx += 256) {
        int o = idx >> 7, c = idx & 127;
        W2f[idx] = f2bf(W2[o * C_H + c] * a1[c]);
    }
    if (tid < C_H) {
        float acc = b2[tid];
        for (int c = 0; c < C_H; ++c) acc += c1[c] * W2[tid * C_H + c];
        b2f[tid] = acc;
    }
}

// ---------------------------------------------------------------------------
// GEMM2a: stats-only pass. z2 = h1@W2f^T + b2f; lrelu; BN2 partials. No store.
// ---------------------------------------------------------------------------
__global__ __launch_bounds__(256) void k_g2a(const float* __restrict__ h,
                                             const unsigned short* __restrict__ Wbf,
                                             const float* __restrict__ b2f,
                                             float* __restrict__ ps,
                                             float* __restrict__ pq) {
    __shared__ __align__(16) unsigned short Ash[64][136];
    __shared__ float sS[4][128];
    __shared__ float sQ[4][128];

    int r0 = blockIdx.x * 64;
    int tid = threadIdx.x;
    int l = tid & 63, w = tid >> 6;

    const float* src = h + (size_t)r0 * C_H;
    for (int i = tid * 4; i < 64 * C_H; i += 1024) {
        float4 v = *(const float4*)&src[i];
        int r = i >> 7, c = i & 127;
        unsigned lo = (unsigned)f2bf(v.x) | ((unsigned)f2bf(v.y) << 16);
        unsigned hi = (unsigned)f2bf(v.z) | ((unsigned)f2bf(v.w) << 16);
        *(uint2*)&Ash[r][c] = make_uint2(lo, hi);
    }
    __syncthreads();

    int cl = l & 15, kh = l >> 4;
    f32x4 acc[8];
#pragma unroll
    for (int n = 0; n < 8; ++n) {
        float bv = b2f[n * 16 + cl];
        acc[n][0] = bv; acc[n][1] = bv; acc[n][2] = bv; acc[n][3] = bv;
    }
    const unsigned short* wb = Wbf + (size_t)cl * C_H + kh * 8;
    for (int kt = 0; kt < 4; ++kt) {
        short8 af = *(const short8*)&Ash[w * 16 + cl][kt * 32 + kh * 8];
#pragma unroll
        for (int n = 0; n < 8; ++n) {
            short8 bf = *(const short8*)(wb + (size_t)n * 16 * C_H + kt * 32);
            acc[n] = __builtin_amdgcn_mfma_f32_16x16x32_bf16(af, bf, acc[n], 0, 0, 0);
        }
    }

    float pss[8], pqs[8];
#pragma unroll
    for (int n = 0; n < 8; ++n) {
        float s = 0.f, q = 0.f;
#pragma unroll
        for (int j = 0; j < 4; ++j) {
            float z = acc[n][j];
            z = z > 0.f ? z : SLOPE * z;
            s += z; q += z * z;
        }
        s += __shfl_xor(s, 16); s += __shfl_xor(s, 32);
        q += __shfl_xor(q, 16); q += __shfl_xor(q, 32);
        pss[n] = s; pqs[n] = q;
    }
    if (l < 16) {
#pragma unroll
        for (int n = 0; n < 8; ++n) {
            sS[w][n * 16 + l] = pss[n];
            sQ[w][n * 16 + l] = pqs[n];
        }
    }
    __syncthreads();
    if (tid < 128) {
        float s = sS[0][tid] + sS[1][tid] + sS[2][tid] + sS[3][tid];
        float q = sQ[0][tid] + sQ[1][tid] + sQ[2][tid] + sQ[3][tid];
        ps[blockIdx.x * C_H + tid] = s;
        pq[blockIdx.x * C_H + tid] = q;
    }
}

// ---------------------------------------------------------------------------
// GEMM2b: recompute z2, apply lrelu + BN2 affine, write d_out in place
// (block reads its own 64 rows before writing them -> race-free).
// Also copies pos_skip / batch_skip slices for this block's rows.
// ---------------------------------------------------------------------------
__global__ __launch_bounds__(256) void k_g2b(float* __restrict__ h,
                                             const unsigned short* __restrict__ Wbf,
                                             const float* __restrict__ b2f,
                                             const float* __restrict__ a2,
                                             const float* __restrict__ c2,
                                             const float* __restrict__ pos_skip,
                                             const int* __restrict__ batch_skip,
                                             float* __restrict__ out_pos,
                                             float* __restrict__ out_batch) {
    __shared__ __align__(16) unsigned short Ash[64][136];

    int r0 = blockIdx.x * 64;
    int tid = threadIdx.x;
    int l = tid & 63, w = tid >> 6;

    // pos/batch copy for this block's rows
    if (tid < 192) out_pos[(size_t)r0 * 3 + tid] = pos_skip[(size_t)r0 * 3 + tid];
    if (tid < 64)  out_batch[r0 + tid] = (float)batch_skip[r0 + tid];

    const float* src = h + (size_t)r0 * C_H;
    for (int i = tid * 4; i < 64 * C_H; i += 1024) {
        float4 v = *(const float4*)&src[i];
        int r = i >> 7, c = i & 127;
        unsigned lo = (unsigned)f2bf(v.x) | ((unsigned)f2bf(v.y) << 16);
        unsigned hi = (unsigned)f2bf(v.z) | ((unsigned)f2bf(v.w) << 16);
        *(uint2*)&Ash[r][c] = make_uint2(lo, hi);
    }
    __syncthreads();

    int cl = l & 15, kh = l >> 4;
    f32x4 acc[8];
#pragma unroll
    for (int n = 0; n < 8; ++n) {
        float bv = b2f[n * 16 + cl];
        acc[n][0] = bv; acc[n][1] = bv; acc[n][2] = bv; acc[n][3] = bv;
    }
    const unsigned short* wb = Wbf + (size_t)cl * C_H + kh * 8;
    for (int kt = 0; kt < 4; ++kt) {
        short8 af = *(const short8*)&Ash[w * 16 + cl][kt * 32 + kh * 8];
#pragma unroll
        for (int n = 0; n < 8; ++n) {
            short8 bf = *(const short8*)(wb + (size_t)n * 16 * C_H + kt * 32);
            acc[n] = __builtin_amdgcn_mfma_f32_16x16x32_bf16(af, bf, acc[n], 0, 0, 0);
        }
    }

#pragma unroll
    for (int n = 0; n < 8; ++n) {
        int col = n * 16 + cl;
        float av = a2[col], cv = c2[col];
#pragma unroll
        for (int j = 0; j < 4; ++j) {
            int row = r0 + w * 16 + kh * 4 + j;
            float z = acc[n][j];
            z = z > 0.f ? z : SLOPE * z;
            h[(size_t)row * C_H + col] = av * z + cv;
        }
    }
}

// ---------------------------------------------------------------------------
extern "C" void kernel_launch(void* const* d_in, const int* in_sizes, int n_in,
                              void* d_out, int out_size, void* d_ws, size_t ws_size,
                              hipStream_t stream) {
    const float* x          = (const float*)d_in[0];
    const float* pos        = (const float*)d_in[1];
    const float* x_skip     = (const float*)d_in[3];
    const float* pos_skip   = (const float*)d_in[4];
    const int*   batch_skip = (const int*)d_in[5];
    const float* W1  = (const float*)d_in[6];
    const float* b1  = (const float*)d_in[7];
    const float* g1  = (const float*)d_in[8];
    const float* be1 = (const float*)d_in[9];
    const float* W2  = (const float*)d_in[10];
    const float* b2  = (const float*)d_in[11];
    const float* g2  = (const float*)d_in[12];
    const float* be2 = (const float*)d_in[13];

    float* out_h     = (float*)d_out;
    float* out_pos   = out_h + (size_t)N_ROWS * C_H;
    float* out_batch = out_pos + (size_t)N_ROWS * 3;

    float* wsf = (float*)d_ws;
    float4* pos4         = (float4*)wsf;                         // 65536 floats
    unsigned short* W1bf = (unsigned short*)(wsf + 65536);       // 24576 us (12288 f)
    unsigned short* W2f  = (unsigned short*)(wsf + 77824);       // 16384 us (8192 f)
    float* b2f = wsf + 86016;                                    // 128
    float* p1s = wsf + 86144;                                    // 131072
    float* p1q = p1s + 131072;
    float* p2s = p1q + 131072;
    float* p2q = p2s + 131072;
    float* a1  = p2q + 131072;
    float* c1  = a1 + 128;
    float* a2  = c1 + 128;
    float* c2  = a2 + 128;

    k_prep<<<64, 256, 0, stream>>>(W1, W1bf, pos, pos4);
    k_fused1<<<GEMM_BLOCKS, 256, 0, stream>>>(pos4, pos_skip, x, x_skip, W1bf, b1,
                                              out_h, p1s, p1q);
    k_reduce<<<C_H, 256, 0, stream>>>(p1s, p1q, g1, be1, a1, c1);
    k_fold<<<1, 256, 0, stream>>>(W2, b2, a1, c1, W2f, b2f);
    k_g2a<<<GEMM_BLOCKS, 256, 0, stream>>>(out_h, W2f, b2f, p2s, p2q);
    k_reduce<<<C_H, 256, 0, stream>>>(p2s, p2q, g2, be2, a2, c2);
    k_g2b<<<GEMM_BLOCKS, 256, 0, stream>>>(out_h, W2f, b2f, a2, c2,
                                           pos_skip, batch_skip, out_pos, out_batch);
}

// Round 5
// 140.531 us; speedup vs baseline: 2.5406x; 1.1515x over previous
//
#include <hip/hip_runtime.h>
#include <math.h>

#define NB 8
#define N_SRC 2048
#define N_DST 8192
#define C_SRC 128
#define C_SKIP 64
#define C_IN 192
#define C_H 128
#define N_ROWS (NB * N_DST)   /* 65536 */
#define BN_EPS 1e-5f
#define SLOPE 0.01f
#define GEMM_BLOCKS (N_ROWS / 64)   /* 1024 */

using short8 = __attribute__((ext_vector_type(8))) short;
using f32x4  = __attribute__((ext_vector_type(4))) float;
using sf16   = __attribute__((ext_vector_type(16))) float;

static __device__ __forceinline__ unsigned short f2bf(float f) {
    unsigned u = __builtin_bit_cast(unsigned, f);
    u = u + 0x7FFFu + ((u >> 16) & 1u);   // round-to-nearest-even
    return (unsigned short)(u >> 16);
}

// ---------------------------------------------------------------------------
// Prep: W1,W2 fp32 -> bf16 (same [out][in] K-contiguous layout);
//       pos -> padded float4 array for scalar-load scan.
// ---------------------------------------------------------------------------
__global__ __launch_bounds__(256) void k_prep(const float* __restrict__ W1,
                                              unsigned short* __restrict__ W1bf,
                                              const float* __restrict__ W2,
                                              unsigned short* __restrict__ W2bf,
                                              const float* __restrict__ pos,
                                              float4* __restrict__ pos4) {
    int gid = blockIdx.x * 256 + threadIdx.x;
    int stride = gridDim.x * 256;
    for (int i = gid; i < C_H * C_IN; i += stride) W1bf[i] = f2bf(W1[i]);
    for (int i = gid; i < C_H * C_H; i += stride)  W2bf[i] = f2bf(W2[i]);
    for (int p = gid; p < NB * N_SRC; p += stride) {
        pos4[p] = make_float4(pos[p * 3 + 0], pos[p * 3 + 1], pos[p * 3 + 2], 0.f);
    }
}

// ---------------------------------------------------------------------------
// Fused KNN + GEMM1. Block = 64 dst rows, 4 waves.
// Phase A: top-3 scan over per-wave 512-pt segment; points streamed through
//          SGPRs via explicit s_load_dwordx16 (scalar pipe, zero LDS/VMEM).
// Phase B: merge 12 candidates; gather+interp A-tile bf16; MFMA; lrelu;
//          h1 fp32 -> out; BN1 partial sums.
// ---------------------------------------------------------------------------
__global__ __launch_bounds__(256) void k_fused1(const float4* __restrict__ pos4,
                                                const float* __restrict__ pos_skip,
                                                const float* __restrict__ x,
                                                const float* __restrict__ x_skip,
                                                const unsigned short* __restrict__ Wbf,
                                                const float* __restrict__ bias,
                                                float* __restrict__ out,
                                                float* __restrict__ ps,
                                                float* __restrict__ pq) {
    __shared__ __align__(16) unsigned short Ash[64][200];   // 25600 B (cd/ci overlay)
    __shared__ float sS[4][128];
    __shared__ float sQ[4][128];
    __shared__ int   midx[64][3];
    __shared__ float mw[64][3];

    float* cd = (float*)&Ash[0][0];                  // [4][64][3] floats
    int*   ci = (int*)((char*)&Ash[0][0] + 3072);    // [4][64][3] ints

    int tid = threadIdx.x;
    int l = tid & 63;
    int w = __builtin_amdgcn_readfirstlane(tid >> 6);  // uniform wave id
    int cloud = blockIdx.x >> 7;
    int r0 = blockIdx.x * 64;

    // ---------------- Phase A: KNN scan (points in SGPRs) ----------------
    int dst = r0 + l;
    float px = pos_skip[dst * 3 + 0];
    float py = pos_skip[dst * 3 + 1];
    float pz = pos_skip[dst * 3 + 2];

    float rr0 = 3.4e38f, rr1 = 3.4e38f, rr2 = 3.4e38f;
    int   ii0 = 0, ii1 = 0, ii2 = 0;

    const char* sp = (const char*)(pos4 + (cloud << 11) + (w << 9));
    for (int g = 0; g < 64; ++g) {          // 64 groups x 8 points
        sf16 A, B;
        asm volatile("s_load_dwordx16 %0, %2, 0x0\n\t"
                     "s_load_dwordx16 %1, %2, 0x40\n\t"
                     "s_waitcnt lgkmcnt(0)"
                     : "=s"(A), "=s"(B)
                     : "s"(sp));
        sp += 128;
        int jb = (w << 9) + g * 8;
#pragma unroll
        for (int k = 0; k < 4; ++k) {
            float dx = px - A[4 * k], dy = py - A[4 * k + 1], dz = pz - A[4 * k + 2];
            float d = fmaf(dx, dx, fmaf(dy, dy, dz * dz));
            if (d < rr2) {
                int jj = jb + k;
                bool c0 = d < rr0, c1 = d < rr1;
                ii2 = c1 ? ii1 : jj;
                rr2 = c1 ? rr1 : d;
                ii1 = c1 ? (c0 ? ii0 : jj) : ii1;
                rr1 = c1 ? (c0 ? rr0 : d) : rr1;
                ii0 = c0 ? jj : ii0;
                rr0 = c0 ? d : rr0;
            }
        }
#pragma unroll
        for (int k = 0; k < 4; ++k) {
            float dx = px - B[4 * k], dy = py - B[4 * k + 1], dz = pz - B[4 * k + 2];
            float d = fmaf(dx, dx, fmaf(dy, dy, dz * dz));
            if (d < rr2) {
                int jj = jb + 4 + k;
                bool c0 = d < rr0, c1 = d < rr1;
                ii2 = c1 ? ii1 : jj;
                rr2 = c1 ? rr1 : d;
                ii1 = c1 ? (c0 ? ii0 : jj) : ii1;
                rr1 = c1 ? (c0 ? rr0 : d) : rr1;
                ii0 = c0 ? jj : ii0;
                rr0 = c0 ? d : rr0;
            }
        }
    }
    cd[(w * 64 + l) * 3 + 0] = rr0; ci[(w * 64 + l) * 3 + 0] = ii0;
    cd[(w * 64 + l) * 3 + 1] = rr1; ci[(w * 64 + l) * 3 + 1] = ii1;
    cd[(w * 64 + l) * 3 + 2] = rr2; ci[(w * 64 + l) * 3 + 2] = ii2;
    __syncthreads();

    // ---------------- merge 12 candidates per dst ----------------
    if (tid < 64) {
        float e0 = 3.4e38f, e1 = 3.4e38f, e2 = 3.4e38f;
        int   m0 = 0, m1 = 0, m2 = 0;
#pragma unroll
        for (int s = 0; s < 4; ++s) {
#pragma unroll
            for (int t = 0; t < 3; ++t) {
                float d = cd[(s * 64 + tid) * 3 + t];
                int  jj = ci[(s * 64 + tid) * 3 + t];
                if (d < e2) {
                    bool c0 = d < e0, c1 = d < e1;
                    m2 = c1 ? m1 : jj;
                    e2 = c1 ? e1 : d;
                    m1 = c1 ? (c0 ? m0 : jj) : m1;
                    e1 = c1 ? (c0 ? e0 : d) : e1;
                    m0 = c0 ? jj : m0;
                    e0 = c0 ? d : e0;
                }
            }
        }
        float w0 = 1.f / fmaxf(e0, 1e-16f);
        float w1 = 1.f / fmaxf(e1, 1e-16f);
        float w2 = 1.f / fmaxf(e2, 1e-16f);
        float inv = 1.f / (w0 + w1 + w2);
        midx[tid][0] = m0; midx[tid][1] = m1; midx[tid][2] = m2;
        mw[tid][0] = w0 * inv; mw[tid][1] = w1 * inv; mw[tid][2] = w2 * inv;
    }
    __syncthreads();

    // ---------------- Phase B: gather + interp -> bf16 A tile ----------------
    const float* xb = x + (size_t)cloud * N_SRC * C_SRC;
    for (int rr = w * 16; rr < w * 16 + 16; ++rr) {
        int j0 = midx[rr][0], j1 = midx[rr][1], j2 = midx[rr][2];
        float w0 = mw[rr][0], w1 = mw[rr][1], w2 = mw[rr][2];
        const float2* x0v = (const float2*)(xb + (size_t)j0 * C_SRC);
        const float2* x1v = (const float2*)(xb + (size_t)j1 * C_SRC);
        const float2* x2v = (const float2*)(xb + (size_t)j2 * C_SRC);
        float2 a = x0v[l], b = x1v[l], c = x2v[l];
        float v0 = w0 * a.x + w1 * b.x + w2 * c.x;
        float v1 = w0 * a.y + w1 * b.y + w2 * c.y;
        ((unsigned*)&Ash[rr][0])[l] = (unsigned)f2bf(v0) | ((unsigned)f2bf(v1) << 16);
        Ash[rr][128 + l] = f2bf(x_skip[(size_t)(r0 + rr) * C_SKIP + l]);
    }
    // waves read only their own 16-row slab -> no barrier needed

    // ---------------- MFMA ----------------
    int cl = l & 15, kh = l >> 4;
    f32x4 acc[8];
#pragma unroll
    for (int n = 0; n < 8; ++n) {
        float bv = bias[n * 16 + cl];
        acc[n][0] = bv; acc[n][1] = bv; acc[n][2] = bv; acc[n][3] = bv;
    }
    const unsigned short* wb = Wbf + (size_t)cl * C_IN + kh * 8;
    for (int kt = 0; kt < 6; ++kt) {
        short8 af = *(const short8*)&Ash[w * 16 + cl][kt * 32 + kh * 8];
#pragma unroll
        for (int n = 0; n < 8; ++n) {
            short8 bf = *(const short8*)(wb + (size_t)n * 16 * C_IN + kt * 32);
            acc[n] = __builtin_amdgcn_mfma_f32_16x16x32_bf16(af, bf, acc[n], 0, 0, 0);
        }
    }

    // ---------------- epilogue: lrelu + store fp32 + BN1 partials ----------------
    float pss[8], pqs[8];
#pragma unroll
    for (int n = 0; n < 8; ++n) {
        float s = 0.f, q = 0.f;
        int col = n * 16 + cl;
#pragma unroll
        for (int j = 0; j < 4; ++j) {
            int row = r0 + w * 16 + kh * 4 + j;
            float z = acc[n][j];
            z = z > 0.f ? z : SLOPE * z;
            out[(size_t)row * C_H + col] = z;
            s += z; q += z * z;
        }
        s += __shfl_xor(s, 16); s += __shfl_xor(s, 32);
        q += __shfl_xor(q, 16); q += __shfl_xor(q, 32);
        pss[n] = s; pqs[n] = q;
    }
    if (l < 16) {
#pragma unroll
        for (int n = 0; n < 8; ++n) {
            sS[w][n * 16 + l] = pss[n];
            sQ[w][n * 16 + l] = pqs[n];
        }
    }
    __syncthreads();
    if (tid < 128) {
        float s = sS[0][tid] + sS[1][tid] + sS[2][tid] + sS[3][tid];
        float q = sQ[0][tid] + sQ[1][tid] + sQ[2][tid] + sQ[3][tid];
        ps[blockIdx.x * C_H + tid] = s;
        pq[blockIdx.x * C_H + tid] = q;
    }
}

// ---------------------------------------------------------------------------
// Per-channel reduce of block partials -> BN affine
// ---------------------------------------------------------------------------
__global__ __launch_bounds__(256) void k_reduce(const float* __restrict__ ps,
                                                const float* __restrict__ pq,
                                                const float* __restrict__ g,
                                                const float* __restrict__ be,
                                                float* __restrict__ a_out,
                                                float* __restrict__ c_out) {
    int col = blockIdx.x;
    float s = 0.f, q = 0.f;
    for (int b = threadIdx.x; b < GEMM_BLOCKS; b += 256) {
        s += ps[b * C_H + col];
        q += pq[b * C_H + col];
    }
    for (int off = 32; off; off >>= 1) {
        s += __shfl_down(s, off);
        q += __shfl_down(q, off);
    }
    __shared__ float rs[4], rq[4];
    if ((threadIdx.x & 63) == 0) { rs[threadIdx.x >> 6] = s; rq[threadIdx.x >> 6] = q; }
    __syncthreads();
    if (threadIdx.x == 0) {
        s = rs[0] + rs[1] + rs[2] + rs[3];
        q = rq[0] + rq[1] + rq[2] + rq[3];
        float mean = s / (float)N_ROWS;
        float var  = q / (float)N_ROWS - mean * mean;
        float a = g[col] * rsqrtf(var + BN_EPS);
        a_out[col] = a;
        c_out[col] = be[col] - mean * a;
    }
}

// ---------------------------------------------------------------------------
// GEMM2a: stats-only pass. Stage Ash = bf16(a1*h1 + c1) (BN1 applied here);
// z2 = Ash@W2bf^T + b2; lrelu; BN2 partials. No store.
// ---------------------------------------------------------------------------
__global__ __launch_bounds__(256) void k_g2a(const float* __restrict__ h,
                                             const unsigned short* __restrict__ Wbf,
                                             const float* __restrict__ b2,
                                             const float* __restrict__ a1,
                                             const float* __restrict__ c1,
                                             float* __restrict__ ps,
                                             float* __restrict__ pq) {
    __shared__ __align__(16) unsigned short Ash[64][136];
    __shared__ float sS[4][128];
    __shared__ float sQ[4][128];

    int r0 = blockIdx.x * 64;
    int tid = threadIdx.x;
    int l = tid & 63, w = tid >> 6;

    const float* src = h + (size_t)r0 * C_H;
    for (int i = tid * 4; i < 64 * C_H; i += 1024) {
        float4 v = *(const float4*)&src[i];
        int r = i >> 7, c = i & 127;
        float4 av = *(const float4*)&a1[c];
        float4 cv = *(const float4*)&c1[c];
        unsigned lo = (unsigned)f2bf(fmaf(av.x, v.x, cv.x)) |
                      ((unsigned)f2bf(fmaf(av.y, v.y, cv.y)) << 16);
        unsigned hi = (unsigned)f2bf(fmaf(av.z, v.z, cv.z)) |
                      ((unsigned)f2bf(fmaf(av.w, v.w, cv.w)) << 16);
        *(uint2*)&Ash[r][c] = make_uint2(lo, hi);
    }
    __syncthreads();

    int cl = l & 15, kh = l >> 4;
    f32x4 acc[8];
#pragma unroll
    for (int n = 0; n < 8; ++n) {
        float bv = b2[n * 16 + cl];
        acc[n][0] = bv; acc[n][1] = bv; acc[n][2] = bv; acc[n][3] = bv;
    }
    const unsigned short* wb = Wbf + (size_t)cl * C_H + kh * 8;
    for (int kt = 0; kt < 4; ++kt) {
        short8 af = *(const short8*)&Ash[w * 16 + cl][kt * 32 + kh * 8];
#pragma unroll
        for (int n = 0; n < 8; ++n) {
            short8 bf = *(const short8*)(wb + (size_t)n * 16 * C_H + kt * 32);
            acc[n] = __builtin_amdgcn_mfma_f32_16x16x32_bf16(af, bf, acc[n], 0, 0, 0);
        }
    }

    float pss[8], pqs[8];
#pragma unroll
    for (int n = 0; n < 8; ++n) {
        float s = 0.f, q = 0.f;
#pragma unroll
        for (int j = 0; j < 4; ++j) {
            float z = acc[n][j];
            z = z > 0.f ? z : SLOPE * z;
            s += z; q += z * z;
        }
        s += __shfl_xor(s, 16); s += __shfl_xor(s, 32);
        q += __shfl_xor(q, 16); q += __shfl_xor(q, 32);
        pss[n] = s; pqs[n] = q;
    }
    if (l < 16) {
#pragma unroll
        for (int n = 0; n < 8; ++n) {
            sS[w][n * 16 + l] = pss[n];
            sQ[w][n * 16 + l] = pqs[n];
        }
    }
    __syncthreads();
    if (tid < 128) {
        float s = sS[0][tid] + sS[1][tid] + sS[2][tid] + sS[3][tid];
        float q = sQ[0][tid] + sQ[1][tid] + sQ[2][tid] + sQ[3][tid];
        ps[blockIdx.x * C_H + tid] = s;
        pq[blockIdx.x * C_H + tid] = q;
    }
}

// ---------------------------------------------------------------------------
// GEMM2b: recompute z2 (same staging), lrelu + BN2 affine, write d_out in
// place (block reads only its own 64 rows -> race-free). Copies pos/batch.
// ---------------------------------------------------------------------------
__global__ __launch_bounds__(256) void k_g2b(float* __restrict__ h,
                                             const unsigned short* __restrict__ Wbf,
                                             const float* __restrict__ b2,
                                             const float* __restrict__ a1,
                                             const float* __restrict__ c1,
                                             const float* __restrict__ a2,
                                             const float* __restrict__ c2,
                                             const float* __restrict__ pos_skip,
                                             const int* __restrict__ batch_skip,
                                             float* __restrict__ out_pos,
                                             float* __restrict__ out_batch) {
    __shared__ __align__(16) unsigned short Ash[64][136];

    int r0 = blockIdx.x * 64;
    int tid = threadIdx.x;
    int l = tid & 63, w = tid >> 6;

    if (tid < 192) out_pos[(size_t)r0 * 3 + tid] = pos_skip[(size_t)r0 * 3 + tid];
    if (tid < 64)  out_batch[r0 + tid] = (float)batch_skip[r0 + tid];

    const float* src = h + (size_t)r0 * C_H;
    for (int i = tid * 4; i < 64 * C_H; i += 1024) {
        float4 v = *(const float4*)&src[i];
        int r = i >> 7, c = i & 127;
        float4 av = *(const float4*)&a1[c];
        float4 cv = *(const float4*)&c1[c];
        unsigned lo = (unsigned)f2bf(fmaf(av.x, v.x, cv.x)) |
                      ((unsigned)f2bf(fmaf(av.y, v.y, cv.y)) << 16);
        unsigned hi = (unsigned)f2bf(fmaf(av.z, v.z, cv.z)) |
                      ((unsigned)f2bf(fmaf(av.w, v.w, cv.w)) << 16);
        *(uint2*)&Ash[r][c] = make_uint2(lo, hi);
    }
    __syncthreads();

    int cl = l & 15, kh = l >> 4;
    f32x4 acc[8];
#pragma unroll
    for (int n = 0; n < 8; ++n) {
        float bv = b2[n * 16 + cl];
        acc[n][0] = bv; acc[n][1] = bv; acc[n][2] = bv; acc[n][3] = bv;
    }
    const unsigned short* wb = Wbf + (size_t)cl * C_H + kh * 8;
    for (int kt = 0; kt < 4; ++kt) {
        short8 af = *(const short8*)&Ash[w * 16 + cl][kt * 32 + kh * 8];
#pragma unroll
        for (int n = 0; n < 8; ++n) {
            short8 bf = *(const short8*)(wb + (size_t)n * 16 * C_H + kt * 32);
            acc[n] = __builtin_amdgcn_mfma_f32_16x16x32_bf16(af, bf, acc[n], 0, 0, 0);
        }
    }

#pragma unroll
    for (int n = 0; n < 8; ++n) {
        int col = n * 16 + cl;
        float av = a2[col], cv = c2[col];
#pragma unroll
        for (int j = 0; j < 4; ++j) {
            int row = r0 + w * 16 + kh * 4 + j;
            float z = acc[n][j];
            z = z > 0.f ? z : SLOPE * z;
            h[(size_t)row * C_H + col] = av * z + cv;
        }
    }
}

// ---------------------------------------------------------------------------
extern "C" void kernel_launch(void* const* d_in, const int* in_sizes, int n_in,
                              void* d_out, int out_size, void* d_ws, size_t ws_size,
                              hipStream_t stream) {
    const float* x          = (const float*)d_in[0];
    const float* pos        = (const float*)d_in[1];
    const float* x_skip     = (const float*)d_in[3];
    const float* pos_skip   = (const float*)d_in[4];
    const int*   batch_skip = (const int*)d_in[5];
    const float* W1  = (const float*)d_in[6];
    const float* b1  = (const float*)d_in[7];
    const float* g1  = (const float*)d_in[8];
    const float* be1 = (const float*)d_in[9];
    const float* W2  = (const float*)d_in[10];
    const float* b2  = (const float*)d_in[11];
    const float* g2  = (const float*)d_in[12];
    const float* be2 = (const float*)d_in[13];

    float* out_h     = (float*)d_out;
    float* out_pos   = out_h + (size_t)N_ROWS * C_H;
    float* out_batch = out_pos + (size_t)N_ROWS * 3;

    float* wsf = (float*)d_ws;
    float4* pos4         = (float4*)wsf;                         // 65536 floats
    unsigned short* W1bf = (unsigned short*)(wsf + 65536);       // 24576 us (12288 f)
    unsigned short* W2bf = (unsigned short*)(wsf + 77824);       // 16384 us (8192 f)
    float* p1s = wsf + 86016;                                    // 131072
    float* p1q = p1s + 131072;
    float* p2s = p1q + 131072;
    float* p2q = p2s + 131072;
    float* a1  = p2q + 131072;
    float* c1  = a1 + 128;
    float* a2  = c1 + 128;
    float* c2  = a2 + 128;

    k_prep<<<64, 256, 0, stream>>>(W1, W1bf, W2, W2bf, pos, pos4);
    k_fused1<<<GEMM_BLOCKS, 256, 0, stream>>>(pos4, pos_skip, x, x_skip, W1bf, b1,
                                              out_h, p1s, p1q);
    k_reduce<<<C_H, 256, 0, stream>>>(p1s, p1q, g1, be1, a1, c1);
    k_g2a<<<GEMM_BLOCKS, 256, 0, stream>>>(out_h, W2bf, b2, a1, c1, p2s, p2q);
    k_reduce<<<C_H, 256, 0, stream>>>(p2s, p2q, g2, be2, a2, c2);
    k_g2b<<<GEMM_BLOCKS, 256, 0, stream>>>(out_h, W2bf, b2, a1, c1, a2, c2,
                                           pos_skip, batch_skip, out_pos, out_batch);
}